// Round 1
// baseline (6632.063 us; speedup 1.0000x reference)
//
#include <hip/hip_runtime.h>
#include <hip/hip_bf16.h>
#include <hip/hip_cooperative_groups.h>

namespace cg = cooperative_groups;

// Problem constants (from reference setup_inputs)
#define Bdim 64
#define Sdim 96
#define Hdim 1024
#define Edim 512
#define Vdim 32000
#define Tdim 32
// d_out layout: decoder_outputs [B,T,V] | h_T [1,B,H] | attentions [B,T,S]
#define O1 65536000L   // B*T*V
#define O2 65601536L   // + B*H
#define TV 1024000L    // T*V

typedef short short8 __attribute__((ext_vector_type(8)));   // 8 bf16 (4 VGPRs)
typedef float f32x4 __attribute__((ext_vector_type(4)));

__device__ __forceinline__ unsigned short f2bf(float f) {
  unsigned u = __builtin_bit_cast(unsigned, f);
  unsigned r = (u + 0x7fffu + ((u >> 16) & 1u)) >> 16;  // RTN-even
  return (unsigned short)r;
}

// ---------- one-time kernels (unchanged, proven) ----------

// phase 1: pu[hc][g] = sum over 128 h of Va[h]*Ua[h][g]   (grid 16 gc x 8 hc)
__global__ void k_u1(const float* __restrict__ Va, const float* __restrict__ Ua,
                     float* __restrict__ pu) {
  int gc = blockIdx.x & 15, hc = blockIdx.x >> 4;
  int lane = threadIdx.x & 63, wv = threadIdx.x >> 6;
  int g = gc * 64 + lane;
  int h0 = hc * 128 + wv * 32;
  float acc = 0.f;
  #pragma unroll 8
  for (int h = h0; h < h0 + 32; ++h) acc = fmaf(Va[h], Ua[(long)h * Hdim + g], acc);
  __shared__ float red[4][64];
  red[wv][lane] = acc;
  __syncthreads();
  if (threadIdx.x < 64)
    pu[hc * Hdim + gc * 64 + threadIdx.x] =
        red[0][threadIdx.x] + red[1][threadIdx.x] + red[2][threadIdx.x] + red[3][threadIdx.x];
}

__global__ void k_u2(const float* __restrict__ pu, float* __restrict__ u) {
  int g = blockIdx.x * 256 + threadIdx.x;
  float s = 0.f;
  #pragma unroll
  for (int i = 0; i < 8; ++i) s += pu[i * Hdim + g];
  u[g] = s;
}

// sc[b,s] = keys[b,s,:] . u   (one wave per (b,s))
__global__ void k_sc(const float* __restrict__ keys, const float* __restrict__ u,
                     float* __restrict__ sc) {
  int wid = blockIdx.x * 4 + (threadIdx.x >> 6);
  int lane = threadIdx.x & 63;
  int b = wid / Sdim, s = wid % Sdim;
  const float* kp = keys + ((long)b * Sdim + s) * Hdim;
  float acc = 0.f;
  #pragma unroll 4
  for (int g = lane; g < Hdim; g += 64) acc = fmaf(kp[g], u[g], acc);
  for (int off = 32; off; off >>= 1) acc += __shfl_down(acc, off);
  if (lane == 0) sc[wid] = acc;
}

// softmax over s (parallel), write w -> wbuf and broadcast attentions for all t
__global__ void k_softmax(const float* __restrict__ sc, float* __restrict__ wbuf,
                          float* __restrict__ attn) {
  int b = blockIdx.x, tid = threadIdx.x;  // 128 threads
  __shared__ float sv[128];
  __shared__ float sw[Sdim];
  float v = (tid < Sdim) ? sc[b * Sdim + tid] : -1e30f;
  sv[tid] = v;
  __syncthreads();
  for (int off = 64; off >= 1; off >>= 1) {
    if (tid < off) sv[tid] = fmaxf(sv[tid], sv[tid + off]);
    __syncthreads();
  }
  float mx = sv[0];
  __syncthreads();
  float e = (tid < Sdim) ? expf(v - mx) : 0.f;
  sv[tid] = e;
  __syncthreads();
  for (int off = 64; off >= 1; off >>= 1) {
    if (tid < off) sv[tid] += sv[tid + off];
    __syncthreads();
  }
  float sm = sv[0];
  if (tid < Sdim) {
    float w = e / sm;
    sw[tid] = w;
    wbuf[b * Sdim + tid] = w;
  }
  __syncthreads();
  for (int i = tid; i < Tdim * Sdim; i += 128)
    attn[(long)b * (Tdim * Sdim) + i] = sw[i % Sdim];
}

// ctxT[h][b] = sum_s w[b][s]*keys[b][s][h].  grid 64 b x 8 slabs, 256 thr.
__global__ void k_ctx(const float* __restrict__ wbuf, const float* __restrict__ keys,
                      float* __restrict__ ctxT) {
  int b = blockIdx.x >> 3, slab = blockIdx.x & 7;
  int tid = threadIdx.x;
  __shared__ float sw[Sdim];
  __shared__ float4 red[8][32];
  if (tid < Sdim) sw[tid] = wbuf[b * Sdim + tid];
  __syncthreads();
  int hq = tid & 31, sg = tid >> 5;  // 32 h-quads (128 h), 8 s-groups of 12
  const float* kp = keys + ((long)b * Sdim + sg * 12) * Hdim + slab * 128 + hq * 4;
  float4 acc = {0.f, 0.f, 0.f, 0.f};
  #pragma unroll
  for (int s = 0; s < 12; ++s) {
    float4 k4 = *(const float4*)(kp + (long)s * Hdim);
    float w = sw[sg * 12 + s];
    acc.x = fmaf(w, k4.x, acc.x); acc.y = fmaf(w, k4.y, acc.y);
    acc.z = fmaf(w, k4.z, acc.z); acc.w = fmaf(w, k4.w, acc.w);
  }
  red[sg][hq] = acc;
  __syncthreads();
  if (tid < 128) {
    int hq2 = tid >> 2, c = tid & 3;
    float s = 0.f;
    #pragma unroll
    for (int i = 0; i < 8; ++i) s += ((const float*)&red[i][hq2])[c];
    ctxT[(slab * 128 + hq2 * 4 + c) * 64 + b] = s;
  }
}

// gctxT[j][b] = b_ih[j] + ctx . W_ih[j, E:].  One block per j, 4-wave K-split.
__global__ void k_gctx(const float* __restrict__ ctxT, const float* __restrict__ Wih,
                       const float* __restrict__ bih, float* __restrict__ gctxT) {
  int j = blockIdx.x;
  int lane = threadIdx.x & 63, wv = threadIdx.x >> 6;
  const float* wp = Wih + (long)j * 1536 + Edim + wv * 256;
  const float* xp = ctxT + (wv * 256) * 64 + lane;
  float acc = 0.f;
  #pragma unroll 8
  for (int h = 0; h < 256; ++h) acc = fmaf(xp[h * 64], wp[h], acc);
  __shared__ float red[4][64];
  red[wv][lane] = acc;
  __syncthreads();
  if (threadIdx.x < 64)
    gctxT[(long)j * 64 + threadIdx.x] = red[0][threadIdx.x] + red[1][threadIdx.x] +
                                        red[2][threadIdx.x] + red[3][threadIdx.x] + bih[j];
}

// hT[k][b] = h0[b][k]; embT[e][b] = relu(emb_table[START=1][e])
__global__ void k_init(const float* __restrict__ h0, const float* __restrict__ embt,
                       float* __restrict__ hT, float* __restrict__ embT) {
  int idx = blockIdx.x * 256 + threadIdx.x;
  if (idx < Bdim * Hdim) {
    int b = idx >> 10, k = idx & 1023;
    hT[k * 64 + b] = h0[idx];
  } else {
    int j = idx - Bdim * Hdim;
    if (j < Edim * 64) {
      int e = j >> 6;
      float x = embt[1 * Edim + e];
      embT[j] = x > 0.f ? x : 0.f;
    }
  }
}

// W_out fp32 -> bf16 copy (one time)
__global__ void k_w2b(const float* __restrict__ W, unsigned short* __restrict__ Wb) {
  long i = ((long)blockIdx.x * 256 + threadIdx.x) * 8;
  float4 a = *(const float4*)(W + i);
  float4 b = *(const float4*)(W + i + 4);
  short8 v;
  v[0] = (short)f2bf(a.x); v[1] = (short)f2bf(a.y); v[2] = (short)f2bf(a.z); v[3] = (short)f2bf(a.w);
  v[4] = (short)f2bf(b.x); v[5] = (short)f2bf(b.y); v[6] = (short)f2bf(b.z); v[7] = (short)f2bf(b.w);
  *(short8*)(Wb + i) = v;
}

template <int WB>
__device__ __forceinline__ short8 loadB(const unsigned short* Bq, const float* Bqf, int off) {
  if (WB) {
    return *(const short8*)(Bq + off);
  } else {
    float4 x = *(const float4*)(Bqf + off);
    float4 y = *(const float4*)(Bqf + off + 4);
    short8 v;
    v[0] = (short)f2bf(x.x); v[1] = (short)f2bf(x.y); v[2] = (short)f2bf(x.z); v[3] = (short)f2bf(x.w);
    v[4] = (short)f2bf(y.x); v[5] = (short)f2bf(y.y); v[6] = (short)f2bf(y.z); v[7] = (short)f2bf(y.w);
    return v;
  }
}

// ---------- fused 32-step decode loop (ONE cooperative dispatch) ----------
// 256 blocks x 512 threads, guaranteed co-resident (1 block/CU: LDS ~51 KB, VGPR<=256).
// Per step: GRU phase (all 256 blocks, 4 hids each) -> grid.sync
//           logits phase (blocks 0..249, 8 waves x 16 cols) -> grid.sync
//           argmax phase (blocks 0..63, one b each) -> grid.sync
// Numerics: identical FMA/reduction orders to the previous per-step kernels.
template <int WB>
__launch_bounds__(512, 2)
__global__ void k_decode(unsigned short* __restrict__ hb,
                         const unsigned short* __restrict__ Wb,
                         const float* __restrict__ Wout,
                         const float* __restrict__ bout,
                         float* __restrict__ out,
                         float* __restrict__ hTa, float* __restrict__ hTb,
                         float* __restrict__ embT,
                         const float* __restrict__ gctxT,
                         const float* __restrict__ Wih,
                         const float* __restrict__ Whh,
                         const float* __restrict__ bhh,
                         float* __restrict__ hrow,
                         float* __restrict__ wsmax,
                         const float* __restrict__ embt) {
  cg::grid_group grid = cg::this_grid();
  __shared__ float red[8][24][64];   // 48 KB: GRU partials (wave, row, b)
  __shared__ float lmax[8][64];      // 2 KB: logits per-wave col-max
  __shared__ float lred[8];
  __shared__ float thr_s;
  __shared__ int qn, cnt, tok_s;
  __shared__ int qblk[32];
  __shared__ int cand[64];
  __shared__ float cval[64];

  const int tid = threadIdx.x, lane = tid & 63, wv = tid >> 6;
  const int bid = blockIdx.x;

  #pragma unroll 1
  for (int t = 0; t < Tdim; ++t) {
    const float* hin = (t & 1) ? hTb : hTa;
    float* hout = (t & 1) ? hTa : hTb;

    // ---------------- GRU phase: 4 hids per block ----------------
    {
      const int hid0 = bid * 4;
      float acc[12];
      // E part: wave wv handles e in [wv*64, wv*64+64)
      #pragma unroll
      for (int r = 0; r < 12; ++r) acc[r] = 0.f;
      {
        const int e0 = wv * 64;
        for (int e = e0; e < e0 + 64; e += 4) {
          float x0 = embT[(e + 0) * 64 + lane];
          float x1 = embT[(e + 1) * 64 + lane];
          float x2 = embT[(e + 2) * 64 + lane];
          float x3 = embT[(e + 3) * 64 + lane];
          #pragma unroll
          for (int r = 0; r < 12; ++r) {
            int row = (r >> 2) * Hdim + hid0 + (r & 3);   // wave-uniform -> s_load
            float4 w = *(const float4*)(Wih + (long)row * 1536 + e);
            acc[r] = fmaf(w.x, x0, acc[r]); acc[r] = fmaf(w.y, x1, acc[r]);
            acc[r] = fmaf(w.z, x2, acc[r]); acc[r] = fmaf(w.w, x3, acc[r]);
          }
        }
        #pragma unroll
        for (int r = 0; r < 12; ++r) red[wv][r][lane] = acc[r];
      }
      // H part: wave wv handles k in [wv*128, wv*128+128)
      #pragma unroll
      for (int r = 0; r < 12; ++r) acc[r] = 0.f;
      {
        const int k0 = wv * 128;
        for (int k = k0; k < k0 + 128; k += 4) {
          float x0 = hin[(k + 0) * 64 + lane];
          float x1 = hin[(k + 1) * 64 + lane];
          float x2 = hin[(k + 2) * 64 + lane];
          float x3 = hin[(k + 3) * 64 + lane];
          #pragma unroll
          for (int r = 0; r < 12; ++r) {
            int row = (r >> 2) * Hdim + hid0 + (r & 3);
            float4 w = *(const float4*)(Whh + (long)row * Hdim + k);
            acc[r] = fmaf(w.x, x0, acc[r]); acc[r] = fmaf(w.y, x1, acc[r]);
            acc[r] = fmaf(w.z, x2, acc[r]); acc[r] = fmaf(w.w, x3, acc[r]);
          }
        }
        #pragma unroll
        for (int r = 0; r < 12; ++r) red[wv][12 + r][lane] = acc[r];
      }
      __syncthreads();
      if (tid < 256) {
        int hh = tid >> 6, b = tid & 63, hid = hid0 + hh;
        float sE0 = 0.f, sE1 = 0.f, sE2 = 0.f, sH0 = 0.f, sH1 = 0.f, sH2 = 0.f;
        #pragma unroll
        for (int w2 = 0; w2 < 8; ++w2) {
          sE0 += red[w2][0 + hh][b];
          sE1 += red[w2][4 + hh][b];
          sE2 += red[w2][8 + hh][b];
          sH0 += red[w2][12 + hh][b];
          sH1 += red[w2][16 + hh][b];
          sH2 += red[w2][20 + hh][b];
        }
        float gr = gctxT[(long)(0 * Hdim + hid) * 64 + b] + sE0;
        float gz = gctxT[(long)(1 * Hdim + hid) * 64 + b] + sE1;
        float gn = gctxT[(long)(2 * Hdim + hid) * 64 + b] + sE2;
        float hr = sH0 + bhh[hid];
        float hz = sH1 + bhh[Hdim + hid];
        float hn = sH2 + bhh[2 * Hdim + hid];
        float rr = 1.f / (1.f + expf(-(gr + hr)));
        float zz = 1.f / (1.f + expf(-(gz + hz)));
        float nn = tanhf(gn + rr * hn);
        float hold = hin[hid * 64 + b];
        float hnew = (1.f - zz) * nn + zz * hold;
        hout[hid * 64 + b] = hnew;
        hrow[b * Hdim + hid] = hnew;
        hb[b * Hdim + hid] = f2bf(hnew);
      }
    }
    grid.sync();

    // ---------------- logits phase: blocks 0..249, 8 waves x 16 cols ----------------
    if (bid < 250) {
      int l15 = lane & 15, quad = lane >> 4;
      int vcol = bid * 128 + wv * 16 + l15;
      f32x4 acc4[4];
      #pragma unroll
      for (int mt = 0; mt < 4; ++mt) acc4[mt] = (f32x4){0.f, 0.f, 0.f, 0.f};
      const unsigned short* A = hb + l15 * Hdim + quad * 8;
      const unsigned short* Bq = WB ? (Wb + (long)vcol * Hdim + quad * 8) : nullptr;
      const float* Bf = WB ? nullptr : (Wout + (long)vcol * Hdim + quad * 8);
      short8 bc = loadB<WB>(Bq, Bf, 0);
      #pragma unroll 4
      for (int ks = 0; ks < 32; ++ks) {
        int k0 = ks * 32;
        short8 bn;
        if (ks < 31) bn = loadB<WB>(Bq, Bf, k0 + 32);
        short8 a0 = *(const short8*)(A + k0);
        short8 a1 = *(const short8*)(A + 16 * Hdim + k0);
        short8 a2 = *(const short8*)(A + 32 * Hdim + k0);
        short8 a3 = *(const short8*)(A + 48 * Hdim + k0);
        acc4[0] = __builtin_amdgcn_mfma_f32_16x16x32_bf16(a0, bc, acc4[0], 0, 0, 0);
        acc4[1] = __builtin_amdgcn_mfma_f32_16x16x32_bf16(a1, bc, acc4[1], 0, 0, 0);
        acc4[2] = __builtin_amdgcn_mfma_f32_16x16x32_bf16(a2, bc, acc4[2], 0, 0, 0);
        acc4[3] = __builtin_amdgcn_mfma_f32_16x16x32_bf16(a3, bc, acc4[3], 0, 0, 0);
        bc = bn;
      }
      float bo = bout[vcol];
      float* Ot = out + (long)t * Vdim;
      #pragma unroll
      for (int mt = 0; mt < 4; ++mt) {
        #pragma unroll
        for (int r = 0; r < 4; ++r) {
          int brow = mt * 16 + quad * 4 + r;  // C/D: row=quad*4+reg, col=l15 (m89-verified)
          float v = acc4[mt][r] + bo;
          Ot[(long)brow * TV + vcol] = v;
          float m = v;
          m = fmaxf(m, __shfl_xor(m, 1));
          m = fmaxf(m, __shfl_xor(m, 2));
          m = fmaxf(m, __shfl_xor(m, 4));
          m = fmaxf(m, __shfl_xor(m, 8));
          if (l15 == 0) lmax[wv][brow] = m;
        }
      }
      __syncthreads();
      if (tid < 64) {
        float m = lmax[0][tid];
        #pragma unroll
        for (int w2 = 1; w2 < 8; ++w2) m = fmaxf(m, lmax[w2][tid]);
        wsmax[tid * 256 + bid] = m;  // [b][block]; block covers 128 cols
      }
    }
    grid.sync();

    // ---------------- argmax + next-emb gather: blocks 0..63 ----------------
    if (t < Tdim - 1) {
      if (bid < 64) {
        int b = bid;
        float mv = (tid < 250) ? wsmax[b * 256 + tid] : -1e30f;
        float m = mv;
        for (int off = 32; off; off >>= 1) m = fmaxf(m, __shfl_down(m, off));
        if (lane == 0) lred[wv] = m;
        if (tid == 0) { qn = 0; cnt = 0; }
        __syncthreads();
        if (tid == 0) {
          float mm = lred[0];
          #pragma unroll
          for (int i = 1; i < 8; ++i) mm = fmaxf(mm, lred[i]);
          thr_s = mm - 0.03f;
        }
        __syncthreads();
        float thr = thr_s;
        if (mv >= thr) {
          int i = atomicAdd(&qn, 1);
          if (i < 32) qblk[i] = tid;
        }
        __syncthreads();
        int QN = min(qn, 32);
        const float* L = out + (long)b * TV + (long)t * Vdim;
        for (int j = tid; j < QN * 128; j += 512) {
          int blk = qblk[j >> 7];
          int v = blk * 128 + (j & 127);
          float val = L[v];
          if (val >= thr) {
            int i = atomicAdd(&cnt, 1);
            if (i < 64) cand[i] = v;
          }
        }
        __syncthreads();
        int C = min(cnt, 64);
        int tok;
        if (C == 1) {
          tok = cand[0];  // margin 0.03 > 2*bf16 error -> no recheck needed
        } else {
          for (int c = 0; c < C; ++c) {
            int v = cand[c];
            const float* wr = Wout + (long)v * Hdim;
            const float* hp = hrow + b * Hdim;
            float p = 0.f;
            #pragma unroll
            for (int k = tid; k < Hdim; k += 512) p = fmaf(hp[k], wr[k], p);
            for (int off = 32; off; off >>= 1) p += __shfl_down(p, off);
            if (lane == 0) lred[wv] = p;
            __syncthreads();
            if (tid == 0) {
              float s = 0.f;
              #pragma unroll
              for (int i = 0; i < 8; ++i) s += lred[i];
              cval[c] = s + bout[v];
            }
            __syncthreads();
          }
          if (tid == 0) {
            float best = -1e30f;
            int bi = 0x7fffffff;
            for (int c = 0; c < C; ++c)
              if (cval[c] > best || (cval[c] == best && cand[c] < bi)) { best = cval[c]; bi = cand[c]; }
            tok_s = bi;
          }
          __syncthreads();
          tok = tok_s;
        }
        // gather next embedding (tid covers e = 0..511)
        {
          float x = embt[(long)tok * Edim + tid];
          embT[tid * 64 + b] = x > 0.f ? x : 0.f;
        }
      }
      grid.sync();
    }
  }
}

// ---------- host ----------

extern "C" void kernel_launch(void* const* d_in, const int* in_sizes, int n_in,
                              void* d_out, int out_size, void* d_ws, size_t ws_size,
                              hipStream_t stream) {
  const float* keys = (const float*)d_in[0];
  const float* h0   = (const float*)d_in[1];
  const float* embt = (const float*)d_in[2];
  const float* Ua   = (const float*)d_in[4];
  const float* Va   = (const float*)d_in[5];
  const float* Wih  = (const float*)d_in[6];
  const float* Whh  = (const float*)d_in[7];
  const float* bih  = (const float*)d_in[8];
  const float* bhh  = (const float*)d_in[9];
  const float* Wout = (const float*)d_in[10];
  const float* bout = (const float*)d_in[11];
  float* out = (float*)d_out;

  char* ws = (char*)d_ws;
  float* u     = (float*)(ws + 0);          // 4 KB
  float* pu    = (float*)(ws + 4096);       // 32 KB
  float* sc    = (float*)(ws + 36864);      // 24 KB
  float* wbuf  = (float*)(ws + 61440);      // 24 KB
  float* ctxT  = (float*)(ws + 86016);      // 256 KB
  float* gctxT = (float*)(ws + 348160);     // 768 KB
  float* hTa   = (float*)(ws + 1134592);    // 256 KB
  float* hTb   = (float*)(ws + 1396736);    // 256 KB
  float* embT  = (float*)(ws + 1658880);    // 128 KB
  float* wsmax = (float*)(ws + 1789952);    // 64 KB
  unsigned short* hb = (unsigned short*)(ws + 1855488);  // 128 KB
  unsigned short* Wb = (unsigned short*)(ws + 1986560);  // 64 MB
  bool useBf = ws_size >= 67522560ull;

  float* houtrow = out + O1;  // h_T slot, overwritten each step (last wins)
  float* attn = out + O2;

  k_u1<<<128, 256, 0, stream>>>(Va, Ua, pu);
  k_u2<<<4, 256, 0, stream>>>(pu, u);
  k_sc<<<1536, 256, 0, stream>>>(keys, u, sc);
  k_softmax<<<64, 128, 0, stream>>>(sc, wbuf, attn);
  k_ctx<<<512, 256, 0, stream>>>(wbuf, keys, ctxT);
  k_gctx<<<3072, 256, 0, stream>>>(ctxT, Wih, bih, gctxT);
  k_init<<<384, 256, 0, stream>>>(h0, embt, hTa, embT);
  if (useBf) k_w2b<<<16000, 256, 0, stream>>>(Wout, Wb);

  void* kargs[] = {(void*)&hb,    (void*)&Wb,    (void*)&Wout, (void*)&bout,
                   (void*)&out,   (void*)&hTa,   (void*)&hTb,  (void*)&embT,
                   (void*)&gctxT, (void*)&Wih,   (void*)&Whh,  (void*)&bhh,
                   (void*)&houtrow, (void*)&wsmax, (void*)&embt};
  const void* fn = useBf ? reinterpret_cast<const void*>(&k_decode<1>)
                         : reinterpret_cast<const void*>(&k_decode<0>);
  hipLaunchCooperativeKernel(fn, dim3(256), dim3(512), kargs, 0, stream);
}

// Round 3
// 4765.788 us; speedup vs baseline: 1.3916x; 1.3916x over previous
//
#include <hip/hip_runtime.h>
#include <hip/hip_bf16.h>

// Problem constants (from reference setup_inputs)
#define Bdim 64
#define Sdim 96
#define Hdim 1024
#define Edim 512
#define Vdim 32000
#define Tdim 32
// d_out layout: decoder_outputs [B,T,V] | h_T [1,B,H] | attentions [B,T,S]
#define O1 65536000L   // B*T*V
#define O2 65601536L   // + B*H
#define TV 1024000L    // T*V

typedef short short8 __attribute__((ext_vector_type(8)));   // 8 bf16 (4 VGPRs)
typedef float f32x4 __attribute__((ext_vector_type(4)));

__device__ __forceinline__ unsigned short f2bf(float f) {
  unsigned u = __builtin_bit_cast(unsigned, f);
  unsigned r = (u + 0x7fffu + ((u >> 16) & 1u)) >> 16;  // RTN-even
  return (unsigned short)r;
}

// ---------- one-time kernels (unchanged, proven) ----------

// phase 1: pu[hc][g] = sum over 128 h of Va[h]*Ua[h][g]   (grid 16 gc x 8 hc)
__global__ void k_u1(const float* __restrict__ Va, const float* __restrict__ Ua,
                     float* __restrict__ pu) {
  int gc = blockIdx.x & 15, hc = blockIdx.x >> 4;
  int lane = threadIdx.x & 63, wv = threadIdx.x >> 6;
  int g = gc * 64 + lane;
  int h0 = hc * 128 + wv * 32;
  float acc = 0.f;
  #pragma unroll 8
  for (int h = h0; h < h0 + 32; ++h) acc = fmaf(Va[h], Ua[(long)h * Hdim + g], acc);
  __shared__ float red[4][64];
  red[wv][lane] = acc;
  __syncthreads();
  if (threadIdx.x < 64)
    pu[hc * Hdim + gc * 64 + threadIdx.x] =
        red[0][threadIdx.x] + red[1][threadIdx.x] + red[2][threadIdx.x] + red[3][threadIdx.x];
}

__global__ void k_u2(const float* __restrict__ pu, float* __restrict__ u) {
  int g = blockIdx.x * 256 + threadIdx.x;
  float s = 0.f;
  #pragma unroll
  for (int i = 0; i < 8; ++i) s += pu[i * Hdim + g];
  u[g] = s;
}

// zero barrier state (reuses the dead pu region). 1 block x 512 threads.
__global__ void k_bz(int* __restrict__ bar) {
  bar[threadIdx.x * 16] = 0;                 // flags, 64B-padded
  if (threadIdx.x == 0) bar[256 * 16] = 0;   // relgen
}

// sc[b,s] = keys[b,s,:] . u   (one wave per (b,s))
__global__ void k_sc(const float* __restrict__ keys, const float* __restrict__ u,
                     float* __restrict__ sc) {
  int wid = blockIdx.x * 4 + (threadIdx.x >> 6);
  int lane = threadIdx.x & 63;
  int b = wid / Sdim, s = wid % Sdim;
  const float* kp = keys + ((long)b * Sdim + s) * Hdim;
  float acc = 0.f;
  #pragma unroll 4
  for (int g = lane; g < Hdim; g += 64) acc = fmaf(kp[g], u[g], acc);
  for (int off = 32; off; off >>= 1) acc += __shfl_down(acc, off);
  if (lane == 0) sc[wid] = acc;
}

// softmax over s (parallel), write w -> wbuf and broadcast attentions for all t
__global__ void k_softmax(const float* __restrict__ sc, float* __restrict__ wbuf,
                          float* __restrict__ attn) {
  int b = blockIdx.x, tid = threadIdx.x;  // 128 threads
  __shared__ float sv[128];
  __shared__ float sw[Sdim];
  float v = (tid < Sdim) ? sc[b * Sdim + tid] : -1e30f;
  sv[tid] = v;
  __syncthreads();
  for (int off = 64; off >= 1; off >>= 1) {
    if (tid < off) sv[tid] = fmaxf(sv[tid], sv[tid + off]);
    __syncthreads();
  }
  float mx = sv[0];
  __syncthreads();
  float e = (tid < Sdim) ? expf(v - mx) : 0.f;
  sv[tid] = e;
  __syncthreads();
  for (int off = 64; off >= 1; off >>= 1) {
    if (tid < off) sv[tid] += sv[tid + off];
    __syncthreads();
  }
  float sm = sv[0];
  if (tid < Sdim) {
    float w = e / sm;
    sw[tid] = w;
    wbuf[b * Sdim + tid] = w;
  }
  __syncthreads();
  for (int i = tid; i < Tdim * Sdim; i += 128)
    attn[(long)b * (Tdim * Sdim) + i] = sw[i % Sdim];
}

// ctxT[h][b] = sum_s w[b][s]*keys[b][s][h].  grid 64 b x 8 slabs, 256 thr.
__global__ void k_ctx(const float* __restrict__ wbuf, const float* __restrict__ keys,
                      float* __restrict__ ctxT) {
  int b = blockIdx.x >> 3, slab = blockIdx.x & 7;
  int tid = threadIdx.x;
  __shared__ float sw[Sdim];
  __shared__ float4 red[8][32];
  if (tid < Sdim) sw[tid] = wbuf[b * Sdim + tid];
  __syncthreads();
  int hq = tid & 31, sg = tid >> 5;  // 32 h-quads (128 h), 8 s-groups of 12
  const float* kp = keys + ((long)b * Sdim + sg * 12) * Hdim + slab * 128 + hq * 4;
  float4 acc = {0.f, 0.f, 0.f, 0.f};
  #pragma unroll
  for (int s = 0; s < 12; ++s) {
    float4 k4 = *(const float4*)(kp + (long)s * Hdim);
    float w = sw[sg * 12 + s];
    acc.x = fmaf(w, k4.x, acc.x); acc.y = fmaf(w, k4.y, acc.y);
    acc.z = fmaf(w, k4.z, acc.z); acc.w = fmaf(w, k4.w, acc.w);
  }
  red[sg][hq] = acc;
  __syncthreads();
  if (tid < 128) {
    int hq2 = tid >> 2, c = tid & 3;
    float s = 0.f;
    #pragma unroll
    for (int i = 0; i < 8; ++i) s += ((const float*)&red[i][hq2])[c];
    ctxT[(slab * 128 + hq2 * 4 + c) * 64 + b] = s;
  }
}

// gctxT[j][b] = b_ih[j] + ctx . W_ih[j, E:].  One block per j, 4-wave K-split.
__global__ void k_gctx(const float* __restrict__ ctxT, const float* __restrict__ Wih,
                       const float* __restrict__ bih, float* __restrict__ gctxT) {
  int j = blockIdx.x;
  int lane = threadIdx.x & 63, wv = threadIdx.x >> 6;
  const float* wp = Wih + (long)j * 1536 + Edim + wv * 256;
  const float* xp = ctxT + (wv * 256) * 64 + lane;
  float acc = 0.f;
  #pragma unroll 8
  for (int h = 0; h < 256; ++h) acc = fmaf(xp[h * 64], wp[h], acc);
  __shared__ float red[4][64];
  red[wv][lane] = acc;
  __syncthreads();
  if (threadIdx.x < 64)
    gctxT[(long)j * 64 + threadIdx.x] = red[0][threadIdx.x] + red[1][threadIdx.x] +
                                        red[2][threadIdx.x] + red[3][threadIdx.x] + bih[j];
}

// hT[k][b] = h0[b][k]; embT[e][b] = relu(emb_table[START=1][e])
__global__ void k_init(const float* __restrict__ h0, const float* __restrict__ embt,
                       float* __restrict__ hT, float* __restrict__ embT) {
  int idx = blockIdx.x * 256 + threadIdx.x;
  if (idx < Bdim * Hdim) {
    int b = idx >> 10, k = idx & 1023;
    hT[k * 64 + b] = h0[idx];
  } else {
    int j = idx - Bdim * Hdim;
    if (j < Edim * 64) {
      int e = j >> 6;
      float x = embt[1 * Edim + e];
      embT[j] = x > 0.f ? x : 0.f;
    }
  }
}

// W_out fp32 -> bf16 copy (one time)
__global__ void k_w2b(const float* __restrict__ W, unsigned short* __restrict__ Wb) {
  long i = ((long)blockIdx.x * 256 + threadIdx.x) * 8;
  float4 a = *(const float4*)(W + i);
  float4 b = *(const float4*)(W + i + 4);
  short8 v;
  v[0] = (short)f2bf(a.x); v[1] = (short)f2bf(a.y); v[2] = (short)f2bf(a.z); v[3] = (short)f2bf(a.w);
  v[4] = (short)f2bf(b.x); v[5] = (short)f2bf(b.y); v[6] = (short)f2bf(b.z); v[7] = (short)f2bf(b.w);
  *(short8*)(Wb + i) = v;
}

template <int WB>
__device__ __forceinline__ short8 loadB(const unsigned short* Bq, const float* Bqf, int off) {
  if (WB) {
    return *(const short8*)(Bq + off);
  } else {
    float4 x = *(const float4*)(Bqf + off);
    float4 y = *(const float4*)(Bqf + off + 4);
    short8 v;
    v[0] = (short)f2bf(x.x); v[1] = (short)f2bf(x.y); v[2] = (short)f2bf(x.z); v[3] = (short)f2bf(x.w);
    v[4] = (short)f2bf(y.x); v[5] = (short)f2bf(y.y); v[6] = (short)f2bf(y.z); v[7] = (short)f2bf(y.w);
    return v;
  }
}

// ---------- custom grid barrier (arrive/poll, no RMW contention) ----------
// bar layout: flags[256] padded to 64B each (bar[bid*16]); relgen at bar[256*16].
// Release/acquire via __builtin_amdgcn_fence(order, "agent") + relaxed flag ops
// (fence-release -> flag store / flag load -> fence-acquire chains are
// transitive, so block A's data is visible to block B through block 0).
// Relaxed spin loads avoid per-iteration cache thrash; one acquire fence on exit.
__device__ __forceinline__ void gbar(int* __restrict__ bar, int gen) {
  const int bid = blockIdx.x, tid = threadIdx.x;
  __syncthreads();
  if (bid != 0) {
    if (tid == 0) {
      __builtin_amdgcn_fence(__ATOMIC_RELEASE, "agent");
      __hip_atomic_store(&bar[bid * 16], gen, __ATOMIC_RELAXED, __HIP_MEMORY_SCOPE_AGENT);
      while (__hip_atomic_load(&bar[256 * 16], __ATOMIC_RELAXED, __HIP_MEMORY_SCOPE_AGENT) < gen)
        __builtin_amdgcn_s_sleep(1);
      __builtin_amdgcn_fence(__ATOMIC_ACQUIRE, "agent");
    }
  } else {
    if (tid > 0 && tid < 256) {
      while (__hip_atomic_load(&bar[tid * 16], __ATOMIC_RELAXED, __HIP_MEMORY_SCOPE_AGENT) < gen)
        __builtin_amdgcn_s_sleep(1);
    }
    __syncthreads();
    if (tid == 0) {
      __builtin_amdgcn_fence(__ATOMIC_ACQ_REL, "agent");
      __hip_atomic_store(&bar[256 * 16], gen, __ATOMIC_RELAXED, __HIP_MEMORY_SCOPE_AGENT);
    }
  }
  __syncthreads();
}

// ---------- fused 32-step decode loop (ONE cooperative dispatch) ----------
// 256 blocks x 512 threads, co-resident (1 block/CU). Phases identical to the
// verified round-1 kernel; only the inter-phase barrier changed (cg::grid.sync
// measured ~60us each -> custom gbar).
template <int WB>
__launch_bounds__(512, 2)
__global__ void k_decode(unsigned short* __restrict__ hb,
                         const unsigned short* __restrict__ Wb,
                         const float* __restrict__ Wout,
                         const float* __restrict__ bout,
                         float* __restrict__ out,
                         float* __restrict__ hTa, float* __restrict__ hTb,
                         float* __restrict__ embT,
                         const float* __restrict__ gctxT,
                         const float* __restrict__ Wih,
                         const float* __restrict__ Whh,
                         const float* __restrict__ bhh,
                         float* __restrict__ hrow,
                         float* __restrict__ wsmax,
                         const float* __restrict__ embt,
                         int* __restrict__ bar) {
  __shared__ float red[8][24][64];   // 48 KB: GRU partials (wave, row, b)
  __shared__ float lmax[8][64];      // 2 KB: logits per-wave col-max
  __shared__ float lred[8];
  __shared__ float thr_s;
  __shared__ int qn, cnt, tok_s;
  __shared__ int qblk[32];
  __shared__ int cand[64];
  __shared__ float cval[64];

  const int tid = threadIdx.x, lane = tid & 63, wv = tid >> 6;
  const int bid = blockIdx.x;
  int gen = 0;

  #pragma unroll 1
  for (int t = 0; t < Tdim; ++t) {
    const float* hin = (t & 1) ? hTb : hTa;
    float* hout = (t & 1) ? hTa : hTb;

    // ---------------- GRU phase: 4 hids per block ----------------
    {
      const int hid0 = bid * 4;
      float acc[12];
      // E part: wave wv handles e in [wv*64, wv*64+64)
      #pragma unroll
      for (int r = 0; r < 12; ++r) acc[r] = 0.f;
      {
        const int e0 = wv * 64;
        for (int e = e0; e < e0 + 64; e += 4) {
          float x0 = embT[(e + 0) * 64 + lane];
          float x1 = embT[(e + 1) * 64 + lane];
          float x2 = embT[(e + 2) * 64 + lane];
          float x3 = embT[(e + 3) * 64 + lane];
          #pragma unroll
          for (int r = 0; r < 12; ++r) {
            int row = (r >> 2) * Hdim + hid0 + (r & 3);   // wave-uniform
            float4 w = *(const float4*)(Wih + (long)row * 1536 + e);
            acc[r] = fmaf(w.x, x0, acc[r]); acc[r] = fmaf(w.y, x1, acc[r]);
            acc[r] = fmaf(w.z, x2, acc[r]); acc[r] = fmaf(w.w, x3, acc[r]);
          }
        }
        #pragma unroll
        for (int r = 0; r < 12; ++r) red[wv][r][lane] = acc[r];
      }
      // H part: wave wv handles k in [wv*128, wv*128+128)
      #pragma unroll
      for (int r = 0; r < 12; ++r) acc[r] = 0.f;
      {
        const int k0 = wv * 128;
        for (int k = k0; k < k0 + 128; k += 4) {
          float x0 = hin[(k + 0) * 64 + lane];
          float x1 = hin[(k + 1) * 64 + lane];
          float x2 = hin[(k + 2) * 64 + lane];
          float x3 = hin[(k + 3) * 64 + lane];
          #pragma unroll
          for (int r = 0; r < 12; ++r) {
            int row = (r >> 2) * Hdim + hid0 + (r & 3);
            float4 w = *(const float4*)(Whh + (long)row * Hdim + k);
            acc[r] = fmaf(w.x, x0, acc[r]); acc[r] = fmaf(w.y, x1, acc[r]);
            acc[r] = fmaf(w.z, x2, acc[r]); acc[r] = fmaf(w.w, x3, acc[r]);
          }
        }
        #pragma unroll
        for (int r = 0; r < 12; ++r) red[wv][12 + r][lane] = acc[r];
      }
      __syncthreads();
      if (tid < 256) {
        int hh = tid >> 6, b = tid & 63, hid = hid0 + hh;
        float sE0 = 0.f, sE1 = 0.f, sE2 = 0.f, sH0 = 0.f, sH1 = 0.f, sH2 = 0.f;
        #pragma unroll
        for (int w2 = 0; w2 < 8; ++w2) {
          sE0 += red[w2][0 + hh][b];
          sE1 += red[w2][4 + hh][b];
          sE2 += red[w2][8 + hh][b];
          sH0 += red[w2][12 + hh][b];
          sH1 += red[w2][16 + hh][b];
          sH2 += red[w2][20 + hh][b];
        }
        float gr = gctxT[(long)(0 * Hdim + hid) * 64 + b] + sE0;
        float gz = gctxT[(long)(1 * Hdim + hid) * 64 + b] + sE1;
        float gn = gctxT[(long)(2 * Hdim + hid) * 64 + b] + sE2;
        float hr = sH0 + bhh[hid];
        float hz = sH1 + bhh[Hdim + hid];
        float hn = sH2 + bhh[2 * Hdim + hid];
        float rr = 1.f / (1.f + expf(-(gr + hr)));
        float zz = 1.f / (1.f + expf(-(gz + hz)));
        float nn = tanhf(gn + rr * hn);
        float hold = hin[hid * 64 + b];
        float hnew = (1.f - zz) * nn + zz * hold;
        hout[hid * 64 + b] = hnew;
        hrow[b * Hdim + hid] = hnew;
        hb[b * Hdim + hid] = f2bf(hnew);
      }
    }
    gbar(bar, ++gen);

    // ---------------- logits phase: blocks 0..249, 8 waves x 16 cols ----------------
    if (bid < 250) {
      int l15 = lane & 15, quad = lane >> 4;
      int vcol = bid * 128 + wv * 16 + l15;
      f32x4 acc4[4];
      #pragma unroll
      for (int mt = 0; mt < 4; ++mt) acc4[mt] = (f32x4){0.f, 0.f, 0.f, 0.f};
      const unsigned short* A = hb + l15 * Hdim + quad * 8;
      const unsigned short* Bq = WB ? (Wb + (long)vcol * Hdim + quad * 8) : nullptr;
      const float* Bf = WB ? nullptr : (Wout + (long)vcol * Hdim + quad * 8);
      short8 bc = loadB<WB>(Bq, Bf, 0);
      #pragma unroll 4
      for (int ks = 0; ks < 32; ++ks) {
        int k0 = ks * 32;
        short8 bn;
        if (ks < 31) bn = loadB<WB>(Bq, Bf, k0 + 32);
        short8 a0 = *(const short8*)(A + k0);
        short8 a1 = *(const short8*)(A + 16 * Hdim + k0);
        short8 a2 = *(const short8*)(A + 32 * Hdim + k0);
        short8 a3 = *(const short8*)(A + 48 * Hdim + k0);
        acc4[0] = __builtin_amdgcn_mfma_f32_16x16x32_bf16(a0, bc, acc4[0], 0, 0, 0);
        acc4[1] = __builtin_amdgcn_mfma_f32_16x16x32_bf16(a1, bc, acc4[1], 0, 0, 0);
        acc4[2] = __builtin_amdgcn_mfma_f32_16x16x32_bf16(a2, bc, acc4[2], 0, 0, 0);
        acc4[3] = __builtin_amdgcn_mfma_f32_16x16x32_bf16(a3, bc, acc4[3], 0, 0, 0);
        bc = bn;
      }
      float bo = bout[vcol];
      float* Ot = out + (long)t * Vdim;
      #pragma unroll
      for (int mt = 0; mt < 4; ++mt) {
        #pragma unroll
        for (int r = 0; r < 4; ++r) {
          int brow = mt * 16 + quad * 4 + r;  // C/D: row=quad*4+reg, col=l15 (m89-verified)
          float v = acc4[mt][r] + bo;
          Ot[(long)brow * TV + vcol] = v;
          float m = v;
          m = fmaxf(m, __shfl_xor(m, 1));
          m = fmaxf(m, __shfl_xor(m, 2));
          m = fmaxf(m, __shfl_xor(m, 4));
          m = fmaxf(m, __shfl_xor(m, 8));
          if (l15 == 0) lmax[wv][brow] = m;
        }
      }
      __syncthreads();
      if (tid < 64) {
        float m = lmax[0][tid];
        #pragma unroll
        for (int w2 = 1; w2 < 8; ++w2) m = fmaxf(m, lmax[w2][tid]);
        wsmax[tid * 256 + bid] = m;  // [b][block]; block covers 128 cols
      }
    }
    gbar(bar, ++gen);

    // ---------------- argmax + next-emb gather: blocks 0..63 ----------------
    if (t < Tdim - 1) {
      if (bid < 64) {
        int b = bid;
        float mv = (tid < 250) ? wsmax[b * 256 + tid] : -1e30f;
        float m = mv;
        for (int off = 32; off; off >>= 1) m = fmaxf(m, __shfl_down(m, off));
        if (lane == 0) lred[wv] = m;
        if (tid == 0) { qn = 0; cnt = 0; }
        __syncthreads();
        if (tid == 0) {
          float mm = lred[0];
          #pragma unroll
          for (int i = 1; i < 8; ++i) mm = fmaxf(mm, lred[i]);
          thr_s = mm - 0.03f;
        }
        __syncthreads();
        float thr = thr_s;
        if (mv >= thr) {
          int i = atomicAdd(&qn, 1);
          if (i < 32) qblk[i] = tid;
        }
        __syncthreads();
        int QN = min(qn, 32);
        const float* L = out + (long)b * TV + (long)t * Vdim;
        for (int j = tid; j < QN * 128; j += 512) {
          int blk = qblk[j >> 7];
          int v = blk * 128 + (j & 127);
          float val = L[v];
          if (val >= thr) {
            int i = atomicAdd(&cnt, 1);
            if (i < 64) cand[i] = v;
          }
        }
        __syncthreads();
        int C = min(cnt, 64);
        int tok;
        if (C == 1) {
          tok = cand[0];  // margin 0.03 > 2*bf16 error -> no recheck needed
        } else {
          for (int c = 0; c < C; ++c) {
            int v = cand[c];
            const float* wr = Wout + (long)v * Hdim;
            const float* hp = hrow + b * Hdim;
            float p = 0.f;
            #pragma unroll
            for (int k = tid; k < Hdim; k += 512) p = fmaf(hp[k], wr[k], p);
            for (int off = 32; off; off >>= 1) p += __shfl_down(p, off);
            if (lane == 0) lred[wv] = p;
            __syncthreads();
            if (tid == 0) {
              float s = 0.f;
              #pragma unroll
              for (int i = 0; i < 8; ++i) s += lred[i];
              cval[c] = s + bout[v];
            }
            __syncthreads();
          }
          if (tid == 0) {
            float best = -1e30f;
            int bi = 0x7fffffff;
            for (int c = 0; c < C; ++c)
              if (cval[c] > best || (cval[c] == best && cand[c] < bi)) { best = cval[c]; bi = cand[c]; }
            tok_s = bi;
          }
          __syncthreads();
          tok = tok_s;
        }
        // gather next embedding (tid covers e = 0..511)
        {
          float x = embt[(long)tok * Edim + tid];
          embT[tid * 64 + b] = x > 0.f ? x : 0.f;
        }
      }
      gbar(bar, ++gen);
    }
  }
}

// ---------- host ----------

extern "C" void kernel_launch(void* const* d_in, const int* in_sizes, int n_in,
                              void* d_out, int out_size, void* d_ws, size_t ws_size,
                              hipStream_t stream) {
  const float* keys = (const float*)d_in[0];
  const float* h0   = (const float*)d_in[1];
  const float* embt = (const float*)d_in[2];
  const float* Ua   = (const float*)d_in[4];
  const float* Va   = (const float*)d_in[5];
  const float* Wih  = (const float*)d_in[6];
  const float* Whh  = (const float*)d_in[7];
  const float* bih  = (const float*)d_in[8];
  const float* bhh  = (const float*)d_in[9];
  const float* Wout = (const float*)d_in[10];
  const float* bout = (const float*)d_in[11];
  float* out = (float*)d_out;

  char* ws = (char*)d_ws;
  float* u     = (float*)(ws + 0);          // 4 KB
  float* pu    = (float*)(ws + 4096);       // 32 KB (dead after k_u2 -> reused as barrier)
  int*   bar   = (int*)(ws + 4096);         // flags[256]*64B + relgen (17 KB < 32 KB)
  float* sc    = (float*)(ws + 36864);      // 24 KB
  float* wbuf  = (float*)(ws + 61440);      // 24 KB
  float* ctxT  = (float*)(ws + 86016);      // 256 KB
  float* gctxT = (float*)(ws + 348160);     // 768 KB
  float* hTa   = (float*)(ws + 1134592);    // 256 KB
  float* hTb   = (float*)(ws + 1396736);    // 256 KB
  float* embT  = (float*)(ws + 1658880);    // 128 KB
  float* wsmax = (float*)(ws + 1789952);    // 64 KB
  unsigned short* hb = (unsigned short*)(ws + 1855488);  // 128 KB
  unsigned short* Wb = (unsigned short*)(ws + 1986560);  // 64 MB
  bool useBf = ws_size >= 67522560ull;

  float* houtrow = out + O1;  // h_T slot, overwritten each step (last wins)
  float* attn = out + O2;

  k_u1<<<128, 256, 0, stream>>>(Va, Ua, pu);
  k_u2<<<4, 256, 0, stream>>>(pu, u);
  k_bz<<<1, 512, 0, stream>>>(bar);
  k_sc<<<1536, 256, 0, stream>>>(keys, u, sc);
  k_softmax<<<64, 128, 0, stream>>>(sc, wbuf, attn);
  k_ctx<<<512, 256, 0, stream>>>(wbuf, keys, ctxT);
  k_gctx<<<3072, 256, 0, stream>>>(ctxT, Wih, bih, gctxT);
  k_init<<<384, 256, 0, stream>>>(h0, embt, hTa, embT);
  if (useBf) k_w2b<<<16000, 256, 0, stream>>>(Wout, Wb);

  void* kargs[] = {(void*)&hb,    (void*)&Wb,    (void*)&Wout, (void*)&bout,
                   (void*)&out,   (void*)&hTa,   (void*)&hTb,  (void*)&embT,
                   (void*)&gctxT, (void*)&Wih,   (void*)&Whh,  (void*)&bhh,
                   (void*)&houtrow, (void*)&wsmax, (void*)&embt, (void*)&bar};
  const void* fn = useBf ? reinterpret_cast<const void*>(&k_decode<1>)
                         : reinterpret_cast<const void*>(&k_decode<0>);
  (void)hipLaunchCooperativeKernel(fn, dim3(256), dim3(512), kargs, 0, stream);
}